// Round 1
// baseline (7048.117 us; speedup 1.0000x reference)
//
#include <hip/hip_runtime.h>
#include <math.h>

#define BS 4
#define HH 480
#define WW 640
#define NC 16
#define CHN 20
#define MM 480
#define VRD 100
#define ZHD 80
#define MINZ 9
#define MAXZ 49

// d_out float offsets
#define OFF0 0            // fp_map_pred (4*1*100*100 = 40000)
#define OFF1 40000        // map_pred (4*20*480*480 = 18432000)  [scratch: V0/Vc early, rotated mid]
#define OFF2 18472000     // current_poses (12)
#define OFF3 18472012     // current_poses (12)
#define OFF4 18472024     // translated (18432000)
#define OFFM 28840000     // scratch maps (4*18*100*100 = 720000), dead tail inside translated slot

__device__ __forceinline__ void pose_params(const float* __restrict__ pose_obs,
                                            const float* __restrict__ poses_last,
                                            int b, float& ct, float& st,
                                            float& stx, float& sty) {
    const float DEG = 57.29577951308232f;
    float o  = poses_last[b*3+2] / DEG;
    float so = sinf(o), co = cosf(o);
    float yy = poses_last[b*3+1] + pose_obs[b*3+0]*so + pose_obs[b*3+1]*co;
    float xx = poses_last[b*3+0] + pose_obs[b*3+0]*co - pose_obs[b*3+1]*so;
    float tt = poses_last[b*3+2] + pose_obs[b*3+2]*DEG;
    tt = fmodf(tt - 180.0f, 360.0f) + 180.0f;
    tt = fmodf(tt + 180.0f, 360.0f) - 180.0f;
    stx = -((xx*100.0f/5.0f) - 240.0f) / 240.0f;
    sty = -((yy*100.0f/5.0f) - 240.0f) / 240.0f;
    float t = (90.0f - tt) * 0.017453292519943295f;
    ct = cosf(t); st = sinf(t);
}

__global__ __launch_bounds__(64) void pose_kernel(const float* __restrict__ pose_obs,
                                                  const float* __restrict__ poses_last,
                                                  float* __restrict__ out) {
    int b = threadIdx.x;
    if (b >= BS) return;
    const float DEG = 57.29577951308232f;
    float o  = poses_last[b*3+2] / DEG;
    float so = sinf(o), co = cosf(o);
    float yy = poses_last[b*3+1] + pose_obs[b*3+0]*so + pose_obs[b*3+1]*co;
    float xx = poses_last[b*3+0] + pose_obs[b*3+0]*co - pose_obs[b*3+1]*so;
    float tt = poses_last[b*3+2] + pose_obs[b*3+2]*DEG;
    tt = fmodf(tt - 180.0f, 360.0f) + 180.0f;
    tt = fmodf(tt + 180.0f, 360.0f) - 180.0f;
    out[OFF2 + b*3+0] = xx; out[OFF2 + b*3+1] = yy; out[OFF2 + b*3+2] = tt;
    out[OFF3 + b*3+0] = xx; out[OFF3 + b*3+1] = yy; out[OFF3 + b*3+2] = tt;
}

__global__ __launch_bounds__(256) void splat_kernel(const float* __restrict__ obs,
                                                    const float* __restrict__ view_angles,
                                                    float* __restrict__ V0,
                                                    float* __restrict__ Vc,
                                                    float foc) {
    int idx = blockIdx.x * blockDim.x + threadIdx.x;
    if (idx >= BS * HH * WW) return;
    int b   = idx / (HH * WW);
    int rem = idx % (HH * WW);
    int h   = rem / WW;
    int w   = rem % WW;
    const float* ob = obs + (size_t)b * CHN * HH * WW;
    float depth = ob[(size_t)3 * HH * WW + rem];
    float gx = (float)w;
    float gz = (float)(HH - 1 - h);
    float Xp = (gx - 319.5f) * depth / foc;
    float Zp = (gz - 239.5f) * depth / foc;
    float a  = view_angles[b] * 0.017453292519943295f;
    float ca = cosf(a), sa = sinf(a);
    float Yv = ca * depth - sa * Zp;
    float Zv = sa * depth + ca * Zp + 155.0f;
    float Xv = Xp + 250.0f;
    float xs = (Xv / 5.0f - 50.0f) / 100.0f * 2.0f;
    float ys = (Yv / 5.0f - 50.0f) / 100.0f * 2.0f;
    float zs = (Zv / 5.0f - 32.0f) / 80.0f * 2.0f;
    float px = xs * 50.0f + 50.0f;
    float py = ys * 50.0f + 50.0f;
    float pz = zs * 40.0f + 40.0f;

    float wx[2], wy[2], wz[2];
    int ixi[2], iyi[2], izi[2];
    {
        float fl = floorf(px);
        #pragma unroll
        for (int i = 0; i < 2; i++) {
            float p = fl + (float)i;
            bool s = (p > 0.0f) && (p < 100.0f);
            wx[i] = s ? (1.0f - fabsf(px - p)) : 0.0f;
            ixi[i] = s ? (int)p : 0;
        }
        fl = floorf(py);
        #pragma unroll
        for (int i = 0; i < 2; i++) {
            float p = fl + (float)i;
            bool s = (p > 0.0f) && (p < 100.0f);
            wy[i] = s ? (1.0f - fabsf(py - p)) : 0.0f;
            iyi[i] = s ? (int)p : 0;
        }
        fl = floorf(pz);
        #pragma unroll
        for (int i = 0; i < 2; i++) {
            float p = fl + (float)i;
            bool s = (p > 0.0f) && (p < 80.0f);
            wz[i] = s ? (1.0f - fabsf(pz - p)) : 0.0f;
            izi[i] = s ? (int)p : 0;
        }
    }

    float semv[NC];
    #pragma unroll
    for (int c = 0; c < NC; c++)
        semv[c] = ob[(size_t)(4 + c) * HH * WW + rem];

    #pragma unroll
    for (int i = 0; i < 2; i++) {
        if (wx[i] == 0.0f) continue;
        #pragma unroll
        for (int j = 0; j < 2; j++) {
            float wxy = wx[i] * wy[j];
            if (wxy == 0.0f) continue;
            int xy = (b * VRD + ixi[i]) * VRD + iyi[j];
            #pragma unroll
            for (int k = 0; k < 2; k++) {
                float wgt = wxy * wz[k];
                if (wgt == 0.0f) continue;
                int vz = izi[k];
                atomicAdd(V0 + (size_t)xy * ZHD + vz, wgt);
                if (vz >= MINZ && vz < MAXZ) {
                    int zr = vz - MINZ;
                    size_t base = ((size_t)b * NC * VRD * VRD +
                                   (size_t)(ixi[i] * VRD + iyi[j])) * 40 + zr;
                    // layout Vc[b][c][x][y][z40]: channel stride = VRD*VRD*40
                    float* p0 = Vc + (size_t)b * NC * VRD * VRD * 40
                                   + (size_t)(ixi[i] * VRD + iyi[j]) * 40 + zr;
                    (void)base;
                    #pragma unroll
                    for (int c = 0; c < NC; c++)
                        atomicAdd(p0 + (size_t)c * VRD * VRD * 40, wgt * semv[c]);
                }
            }
        }
    }
}

__global__ __launch_bounds__(256) void reduce_kernel(const float* __restrict__ V0,
                                                     const float* __restrict__ Vc,
                                                     float* __restrict__ maps,
                                                     float* __restrict__ out0) {
    int idx = blockIdx.x * blockDim.x + threadIdx.x;
    if (idx >= BS * 17 * VRD * VRD) return;
    int b   = idx / (17 * VRD * VRD);
    int rem = idx % (17 * VRD * VRD);
    int c   = rem / (VRD * VRD);
    int rr  = rem % (VRD * VRD);
    int xj  = rr / VRD;
    int yi  = rr % VRD;
    if (c == 0) {
        const float* p = V0 + (size_t)((b * VRD + xj) * VRD + yi) * ZHD;
        float s_all = 0.0f, s_agg = 0.0f;
        for (int z = 0; z < ZHD; z++) {
            float r = rintf(p[z]);
            s_all += r;
            if (z >= MINZ && z < MAXZ) s_agg += r;
        }
        float fm = fminf(fmaxf(s_agg, 0.0f), 1.0f);
        float fe = fminf(fmaxf(s_all, 0.0f), 1.0f);
        maps[((size_t)b * 18 + 0) * VRD * VRD + yi * VRD + xj] = fm;
        maps[((size_t)b * 18 + 1) * VRD * VRD + yi * VRD + xj] = fe;
        out0[(size_t)b * VRD * VRD + yi * VRD + xj] = fm;
    } else {
        const float* p = Vc + ((size_t)(b * NC + (c - 1)) * VRD * VRD
                               + (size_t)(xj * VRD + yi)) * 40;
        float s = 0.0f;
        for (int z = 0; z < 40; z++) s += rintf(p[z]);
        float v = fminf(fmaxf(s / 5.0f, 0.0f), 1.0f);
        maps[((size_t)b * 18 + (c + 1)) * VRD * VRD + yi * VRD + xj] = v;
    }
}

__global__ __launch_bounds__(256) void rotate_kernel(const float* __restrict__ maps,
                                                     const float* __restrict__ pose_obs,
                                                     const float* __restrict__ poses_last,
                                                     float* __restrict__ rot) {
    int idx = blockIdx.x * blockDim.x + threadIdx.x;
    if (idx >= BS * MM * MM) return;
    int b   = idx / (MM * MM);
    int rem = idx % (MM * MM);
    int y   = rem / MM;
    int x   = rem % MM;
    float ct, st, stx, sty;
    pose_params(pose_obs, poses_last, b, ct, st, stx, sty);
    float Xg = -1.0f + (float)x * (2.0f / 479.0f);
    float Yg = -1.0f + (float)y * (2.0f / 479.0f);
    float gx = ct * Xg - st * Yg;
    float gy = st * Xg + ct * Yg;
    float xf = (gx + 1.0f) * 0.5f * 479.0f;
    float yf = (gy + 1.0f) * 0.5f * 479.0f;
    float x0 = floorf(xf), y0 = floorf(yf);
    float fx = xf - x0, fy = yf - y0;
    float cw[4] = {(1.0f - fx) * (1.0f - fy), fx * (1.0f - fy),
                   (1.0f - fx) * fy,          fx * fy};
    float cx[4] = {x0, x0 + 1.0f, x0, x0 + 1.0f};
    float cy[4] = {y0, y0, y0 + 1.0f, y0 + 1.0f};
    float acc[18];
    #pragma unroll
    for (int m = 0; m < 18; m++) acc[m] = 0.0f;
    #pragma unroll
    for (int k = 0; k < 4; k++) {
        float fxk = cx[k], fyk = cy[k];
        if (!(fxk >= 0.0f && fxk <= 479.0f && fyk >= 0.0f && fyk <= 479.0f)) continue;
        int ix = (int)fxk, iy = (int)fyk;
        if (iy < 240 || iy >= 340 || ix < 190 || ix >= 290) continue;
        int mi = iy - 240, mj = ix - 190;
        float w = cw[k];
        const float* mp = maps + (size_t)b * 18 * VRD * VRD + mi * VRD + mj;
        #pragma unroll
        for (int m = 0; m < 18; m++) acc[m] += w * mp[(size_t)m * VRD * VRD];
    }
    size_t obase = ((size_t)b * CHN) * MM * MM + (size_t)y * MM + x;
    rot[obase + (size_t)0 * MM * MM] = acc[0];
    rot[obase + (size_t)1 * MM * MM] = acc[1];
    rot[obase + (size_t)2 * MM * MM] = 0.0f;
    rot[obase + (size_t)3 * MM * MM] = 0.0f;
    #pragma unroll
    for (int m = 2; m < 18; m++)
        rot[obase + (size_t)(m + 2) * MM * MM] = acc[m];
}

__global__ __launch_bounds__(256) void translate_kernel(const float* __restrict__ rot,
                                                        const float* __restrict__ pose_obs,
                                                        const float* __restrict__ poses_last,
                                                        float* __restrict__ tr) {
    int idx = blockIdx.x * blockDim.x + threadIdx.x;
    if (idx >= BS * MM * MM) return;
    int b   = idx / (MM * MM);
    int rem = idx % (MM * MM);
    int y   = rem / MM;
    int x   = rem % MM;
    float ct, st, stx, sty;
    pose_params(pose_obs, poses_last, b, ct, st, stx, sty);
    float Xg = -1.0f + (float)x * (2.0f / 479.0f);
    float Yg = -1.0f + (float)y * (2.0f / 479.0f);
    float xf = (Xg + stx + 1.0f) * 0.5f * 479.0f;
    float yf = (Yg + sty + 1.0f) * 0.5f * 479.0f;
    float x0 = floorf(xf), y0 = floorf(yf);
    float fx = xf - x0, fy = yf - y0;
    float cw[4] = {(1.0f - fx) * (1.0f - fy), fx * (1.0f - fy),
                   (1.0f - fx) * fy,          fx * fy};
    float cxs[4] = {x0, x0 + 1.0f, x0, x0 + 1.0f};
    float cys[4] = {y0, y0, y0 + 1.0f, y0 + 1.0f};
    bool vk[4]; int offk[4];
    #pragma unroll
    for (int k = 0; k < 4; k++) {
        vk[k] = (cxs[k] >= 0.0f && cxs[k] <= 479.0f && cys[k] >= 0.0f && cys[k] <= 479.0f);
        offk[k] = vk[k] ? ((int)cys[k] * MM + (int)cxs[k]) : 0;
    }
    #pragma unroll
    for (int c = 0; c < CHN; c++) {
        const float* rp = rot + ((size_t)b * CHN + c) * MM * MM;
        float v = 0.0f;
        #pragma unroll
        for (int k = 0; k < 4; k++)
            if (vk[k]) v += cw[k] * rp[offk[k]];
        tr[((size_t)b * CHN + c) * MM * MM + (size_t)y * MM + x] = v;
    }
}

__global__ __launch_bounds__(256) void max_kernel(const float* __restrict__ maps_last,
                                                  const float* __restrict__ tr,
                                                  float* __restrict__ mp) {
    int i = blockIdx.x * blockDim.x + threadIdx.x;
    int n4 = BS * CHN * MM * MM / 4;
    if (i >= n4) return;
    float4 a = ((const float4*)maps_last)[i];
    float4 t = ((const float4*)tr)[i];
    float4 r;
    r.x = fmaxf(a.x, t.x);
    r.y = fmaxf(a.y, t.y);
    r.z = fmaxf(a.z, t.z);
    r.w = fmaxf(a.w, t.w);
    ((float4*)mp)[i] = r;
}

extern "C" void kernel_launch(void* const* d_in, const int* in_sizes, int n_in,
                              void* d_out, int out_size, void* d_ws, size_t ws_size,
                              hipStream_t stream) {
    const float* obs         = (const float*)d_in[0];
    const float* pose_obs    = (const float*)d_in[1];
    const float* maps_last   = (const float*)d_in[2];
    const float* poses_last  = (const float*)d_in[3];
    const float* view_angles = (const float*)d_in[4];
    float* out = (float*)d_out;

    // scratch (inside d_out, regions dead until later stages):
    float* V0   = out + OFF1;                              // 4*100*100*80   = 3,200,000
    float* Vc   = V0 + (size_t)BS * VRD * VRD * ZHD;       // 4*16*100*100*40 = 25,600,000
    float* maps = out + OFFM;                              // 4*18*100*100   = 720,000

    // zero voxel grid (115.2 MB)
    hipMemsetAsync(V0, 0, (size_t)(BS * VRD * VRD * ZHD + BS * NC * VRD * VRD * 40)
                          * sizeof(float), stream);

    const float foc = (float)(320.0 / tan(39.5 * M_PI / 180.0));

    int npix = BS * HH * WW;
    splat_kernel<<<(npix + 255) / 256, 256, 0, stream>>>(obs, view_angles, V0, Vc, foc);

    int nred = BS * 17 * VRD * VRD;
    reduce_kernel<<<(nred + 255) / 256, 256, 0, stream>>>(V0, Vc, maps, out + OFF0);

    pose_kernel<<<1, 64, 0, stream>>>(pose_obs, poses_last, out);

    int nmap = BS * MM * MM;
    rotate_kernel<<<(nmap + 255) / 256, 256, 0, stream>>>(maps, pose_obs, poses_last,
                                                          out + OFF1);
    translate_kernel<<<(nmap + 255) / 256, 256, 0, stream>>>(out + OFF1, pose_obs,
                                                             poses_last, out + OFF4);
    int n4 = BS * CHN * MM * MM / 4;
    max_kernel<<<(n4 + 255) / 256, 256, 0, stream>>>(maps_last, out + OFF4, out + OFF1);
}